// Round 1
// baseline (5748.793 us; speedup 1.0000x reference)
//
#include <hip/hip_runtime.h>
#include <hip/hip_bf16.h>

#define SEQ   512
#define BATCH 128
#define EMBD  256
#define HIDD  512
#define NCLS  16

__device__ __forceinline__ float bfu(unsigned short u) {
    return __uint_as_float(((unsigned int)u) << 16);
}

// Pack W_hh [HID][HID] -> Wpk bf16 laid out as [k/4][j][4]  (ushort4 per (k4,j))
// Pack W_ih [HID][EMB] -> Wipk bf16 laid out as [e/4][j][4]
// bias[j] = b_ih[j] + b_hh[j]
__global__ void cvt_kernel(const float* __restrict__ W_ih,
                           const float* __restrict__ W_hh,
                           const float* __restrict__ b_ih,
                           const float* __restrict__ b_hh,
                           unsigned short* __restrict__ Wpk,
                           unsigned short* __restrict__ Wipk,
                           float* __restrict__ bias) {
    const int NW = HIDD * HIDD;
    const int NI = HIDD * EMBD;
    int gid = blockIdx.x * blockDim.x + threadIdx.x;
    if (gid < NW) {
        int j = gid >> 9;            // row of W_hh
        int k = gid & (HIDD - 1);    // col of W_hh
        __hip_bfloat16 hb = __float2bfloat16(W_hh[gid]);
        Wpk[((k >> 2) * HIDD + j) * 4 + (k & 3)] = *reinterpret_cast<unsigned short*>(&hb);
    } else if (gid < NW + NI) {
        int g = gid - NW;
        int j = g >> 8;              // row of W_ih
        int e = g & (EMBD - 1);      // col of W_ih
        __hip_bfloat16 hb = __float2bfloat16(W_ih[g]);
        Wipk[((e >> 2) * HIDD + j) * 4 + (e & 3)] = *reinterpret_cast<unsigned short*>(&hb);
    } else if (gid < NW + NI + HIDD) {
        int j = gid - NW - NI;
        bias[j] = b_ih[j] + b_hh[j];
    }
}

// One workgroup per batch element. 512 threads: thread j owns hidden unit j.
// h lives in LDS; per step: stage emb row -> fused input proj + recurrent matvec
// -> tanh -> write back. No inter-WG communication anywhere.
__global__ __launch_bounds__(512) void rnn_kernel(
    const int*            __restrict__ x,
    const float*          __restrict__ emb,
    const unsigned short* __restrict__ Wpk,
    const unsigned short* __restrict__ Wipk,
    const float*          __restrict__ bias,
    const float*          __restrict__ W_fc,
    const float*          __restrict__ b_fc,
    float*                __restrict__ out) {

    __shared__ __align__(16) float hL[HIDD];
    __shared__ __align__(16) float xe[EMBD];
    __shared__ float red[512];

    const int tid = threadIdx.x;
    const int b   = blockIdx.x;
    const int j   = tid;

    hL[j] = 0.0f;
    const float bj = bias[j];

    const ushort4* Wp4 = reinterpret_cast<const ushort4*>(Wpk);
    const ushort4* Wi4 = reinterpret_cast<const ushort4*>(Wipk);

    for (int t = 0; t < SEQ; ++t) {
        const int tok = x[t * BATCH + b];   // wave-uniform -> scalar load
        if (tid < EMBD) {
            xe[tid] = emb[tok * EMBD + tid];  // coalesced row gather
        }
        __syncthreads();   // xe ready; prev-step h writes visible

        float a0 = bj, a1 = 0.0f;   // two accumulation chains for ILP

        // input projection: sum_e xe[e] * W_ih[j][e]
        #pragma unroll 8
        for (int e4 = 0; e4 < EMBD / 4; ++e4) {
            const float4 xv = *reinterpret_cast<const float4*>(&xe[e4 * 4]);
            const ushort4 w = Wi4[e4 * HIDD + j];   // 8B/lane coalesced
            a0 += xv.x * bfu(w.x) + xv.y * bfu(w.y);
            a1 += xv.z * bfu(w.z) + xv.w * bfu(w.w);
        }
        // recurrent matvec: sum_k h[k] * W_hh[j][k]
        #pragma unroll 8
        for (int k4 = 0; k4 < HIDD / 4; ++k4) {
            const float4 hv = *reinterpret_cast<const float4*>(&hL[k4 * 4]);
            const ushort4 w = Wp4[k4 * HIDD + j];   // 8B/lane coalesced
            a0 += hv.x * bfu(w.x) + hv.y * bfu(w.y);
            a1 += hv.z * bfu(w.z) + hv.w * bfu(w.w);
        }

        __syncthreads();   // all reads of hL done
        hL[j] = tanhf(a0 + a1);
        // next iteration's first barrier orders these writes before reads
    }
    __syncthreads();   // final h ready

    // FC epilogue: out[b][c] = sum_j h[j] * W_fc[c][j] + b_fc[c]
    {
        const int c  = tid >> 5;      // 0..15
        const int ks = tid & 31;      // 0..31
        float p = 0.0f;
        #pragma unroll
        for (int jj = 0; jj < HIDD / 32; ++jj) {
            const int jd = ks * (HIDD / 32) + jj;
            p += hL[jd] * W_fc[c * HIDD + jd];
        }
        red[tid] = p;
        __syncthreads();
        if (tid < NCLS) {
            float s = b_fc[tid];
            #pragma unroll
            for (int i = 0; i < 32; ++i) s += red[tid * 32 + i];
            out[b * NCLS + tid] = s;
        }
    }
}

extern "C" void kernel_launch(void* const* d_in, const int* in_sizes, int n_in,
                              void* d_out, int out_size, void* d_ws, size_t ws_size,
                              hipStream_t stream) {
    const int*   x    = (const int*)  d_in[0];
    const float* emb  = (const float*)d_in[1];
    const float* W_ih = (const float*)d_in[2];
    const float* W_hh = (const float*)d_in[3];
    const float* b_ih = (const float*)d_in[4];
    const float* b_hh = (const float*)d_in[5];
    const float* W_fc = (const float*)d_in[6];
    const float* b_fc = (const float*)d_in[7];
    float* out = (float*)d_out;

    unsigned short* Wpk  = (unsigned short*)d_ws;                 // 512 KB
    unsigned short* Wipk = Wpk + HIDD * HIDD;                     // 256 KB
    float*          bias = (float*)(Wipk + HIDD * EMBD);          // 2 KB

    const int total = HIDD * HIDD + HIDD * EMBD + HIDD;
    cvt_kernel<<<(total + 255) / 256, 256, 0, stream>>>(W_ih, W_hh, b_ih, b_hh,
                                                        Wpk, Wipk, bias);
    rnn_kernel<<<BATCH, 512, 0, stream>>>(x, emb, Wpk, Wipk, bias, W_fc, b_fc, out);
}

// Round 2
// 1683.541 us; speedup vs baseline: 3.4147x; 3.4147x over previous
//
#include <hip/hip_runtime.h>
#include <hip/hip_bf16.h>

#define SEQ   512
#define BATCH 128
#define EMBD  256
#define HIDD  512
#define NCLS  16
#define VOCAB 32000

typedef __attribute__((ext_vector_type(8))) short  short8;
typedef __attribute__((ext_vector_type(4))) float  f32x4;

__device__ __forceinline__ float bfu(unsigned short u) {
    return __uint_as_float(((unsigned int)u) << 16);
}
__device__ __forceinline__ unsigned short f2bf(float f) {
    __hip_bfloat16 h = __float2bfloat16(f);
    return *reinterpret_cast<unsigned short*>(&h);
}
__device__ __forceinline__ float tanh_fast(float x) {
    // (e^{2x}-1)/(e^{2x}+1) == tanh(x) exactly; clamp to avoid inf
    float xc = fminf(fmaxf(x, -12.f), 12.f);
    float e  = __expf(2.f * xc);
    return 1.f - 2.f / (e + 1.f);
}
__device__ __forceinline__ float ep_load(const float* p)          { return *p; }
__device__ __forceinline__ float ep_load(const unsigned short* p) { return bfu(*p); }
__device__ __forceinline__ void  ep_store(float* p, float v)          { *p = v; }
__device__ __forceinline__ void  ep_store(unsigned short* p, float v) { *p = f2bf(v); }

// ---------------------------------------------------------------------------
// W_hh fp32 -> bf16, same row-major layout.
__global__ void cvt_whh(const float* __restrict__ W, unsigned short* __restrict__ Wb) {
    int i = blockIdx.x * 256 + threadIdx.x;
    if (i < HIDD * HIDD) Wb[i] = f2bf(W[i]);
}

// ---------------------------------------------------------------------------
// EP[v][j] = sum_e emb[v][e]*W_ih[j][e] + b_ih[j] + b_hh[j]
// MFMA 16x16x32 bf16. Block = 256 thr (4 waves); wave w does mtile=bx*4+w,
// ntile = by. grid = (VOCAB/64, HIDD/16).
template <typename EPT>
__global__ __launch_bounds__(256) void ep_gemm(
    const float* __restrict__ emb, const float* __restrict__ W_ih,
    const float* __restrict__ b_ih, const float* __restrict__ b_hh,
    EPT* __restrict__ EP) {
    const int w    = threadIdx.x >> 6;
    const int l    = threadIdx.x & 63;
    const int ln16 = l & 15;
    const int lk   = l >> 4;
    const int mtile = blockIdx.x * 4 + w;   // 0..1999
    const int ntile = blockIdx.y;           // 0..31
    const int arow  = mtile * 16 + ln16;
    const int brow  = ntile * 16 + ln16;

    f32x4 acc = {0.f, 0.f, 0.f, 0.f};
    #pragma unroll
    for (int kk = 0; kk < EMBD / 32; ++kk) {
        const int k0 = kk * 32 + lk * 8;
        const float4 a0 = *reinterpret_cast<const float4*>(emb  + arow * EMBD + k0);
        const float4 a1 = *reinterpret_cast<const float4*>(emb  + arow * EMBD + k0 + 4);
        const float4 c0 = *reinterpret_cast<const float4*>(W_ih + brow * EMBD + k0);
        const float4 c1 = *reinterpret_cast<const float4*>(W_ih + brow * EMBD + k0 + 4);
        short8 af, bf_;
        af[0]=(short)f2bf(a0.x); af[1]=(short)f2bf(a0.y); af[2]=(short)f2bf(a0.z); af[3]=(short)f2bf(a0.w);
        af[4]=(short)f2bf(a1.x); af[5]=(short)f2bf(a1.y); af[6]=(short)f2bf(a1.z); af[7]=(short)f2bf(a1.w);
        bf_[0]=(short)f2bf(c0.x); bf_[1]=(short)f2bf(c0.y); bf_[2]=(short)f2bf(c0.z); bf_[3]=(short)f2bf(c0.w);
        bf_[4]=(short)f2bf(c1.x); bf_[5]=(short)f2bf(c1.y); bf_[6]=(short)f2bf(c1.z); bf_[7]=(short)f2bf(c1.w);
        acc = __builtin_amdgcn_mfma_f32_16x16x32_bf16(af, bf_, acc, 0, 0, 0);
    }
    const int col  = ntile * 16 + ln16;
    const float bias = b_ih[col] + b_hh[col];
    #pragma unroll
    for (int r = 0; r < 4; ++r) {
        const int row = mtile * 16 + lk * 4 + r;   // C/D: row=(lane>>4)*4+reg, col=lane&15
        ep_store(EP + (size_t)row * HIDD + col, acc[r] + bias);
    }
}

// ---------------------------------------------------------------------------
// Weights-stationary RNN. 8 WGs x 16 batch rows, 512 thr (8 waves).
// Wave w owns output cols jw=w*64 .. +63: tiles 0-2 weights in 192 VGPRs,
// tile 3 in a 128KB LDS buffer (fragment order). h kept in LDS in A-fragment
// order (16KB): frag (kk,l,i) = h[l&15][kk*32+(l>>4)*8+i].
template <typename EPT>
__global__ __launch_bounds__(512, 2) void rnn_mfma(
    const int*            __restrict__ x,
    const unsigned short* __restrict__ Whh,   // bf16 [512][512]
    const EPT*            __restrict__ EP,    // [VOCAB][512]
    const float*          __restrict__ W_fc,
    const float*          __restrict__ b_fc,
    float*                __restrict__ out) {

    __shared__ unsigned short hB[16 * HIDD];          // 16 KB
    __shared__ unsigned short BT[8 * 16 * 64 * 8];    // 128 KB

    const int tid  = threadIdx.x;
    const int w    = tid >> 6;
    const int l    = tid & 63;
    const int ln16 = l & 15;
    const int lk   = l >> 4;
    const int jw   = w * 64;
    const int b0   = blockIdx.x * 16;

    // zero h
    for (int i = tid; i < 16 * HIDD; i += 512) hB[i] = 0;

    // stage tile-3 weights into LDS in fragment order:
    // BT[((w2*16+kk)*64 + l2)*8 + i] = Whh[w2*64+48+(l2&15)][kk*32+(l2>>4)*8+i]
    for (int idx = tid; idx < 8 * 16 * 64; idx += 512) {
        const int w2 = idx >> 10;
        const int kk = (idx >> 6) & 15;
        const int l2 = idx & 63;
        *reinterpret_cast<short8*>(&BT[idx * 8]) =
            *reinterpret_cast<const short8*>(
                Whh + (w2 * 64 + 48 + (l2 & 15)) * HIDD + kk * 32 + (l2 >> 4) * 8);
    }

    // register-resident B fragments for tiles 0..2
    short8 bfrag[3][16];
    #pragma unroll
    for (int tile = 0; tile < 3; ++tile) {
        const int row = jw + tile * 16 + ln16;
        #pragma unroll
        for (int kk = 0; kk < 16; ++kk)
            bfrag[tile][kk] = *reinterpret_cast<const short8*>(
                Whh + row * HIDD + kk * 32 + lk * 8);
    }

    // per-lane write byte-bases into fragment-order hB, one per tile:
    // byte(row=lk*4+r, col) = (col>>5)*1024 + ((col>>3)&3)*256 + lk*64 + r*16 + (col&7)*2
    unsigned Bb[4];
    #pragma unroll
    for (int tile = 0; tile < 4; ++tile) {
        const int col = jw + tile * 16 + ln16;
        Bb[tile] = (unsigned)((col >> 5) * 1024 + ((col >> 3) & 3) * 256 +
                              lk * 64 + (col & 7) * 2);
    }

    const short8* hAp = reinterpret_cast<const short8*>(hB) + l;
    const short8* btp = reinterpret_cast<const short8*>(BT) + w * 16 * 64 + l;
    char*         hc  = reinterpret_cast<char*>(hB);

    __syncthreads();

    for (int t = 0; t < SEQ; ++t) {
        // tokens for this lane-group's 4 C/D rows (16B aligned int4)
        const int4 tok4 = *reinterpret_cast<const int4*>(x + t * BATCH + b0 + lk * 4);
        const int tk[4] = {tok4.x, tok4.y, tok4.z, tok4.w};
        // EP gather, issued before the MFMA loop so latency hides under it
        float ep[4][4];
        #pragma unroll
        for (int r = 0; r < 4; ++r) {
            const EPT* rowp = EP + (size_t)tk[r] * HIDD + jw + ln16;
            #pragma unroll
            for (int tile = 0; tile < 4; ++tile)
                ep[r][tile] = ep_load(rowp + tile * 16);
        }

        f32x4 acc[4] = {{0,0,0,0},{0,0,0,0},{0,0,0,0},{0,0,0,0}};
        #pragma unroll
        for (int kk = 0; kk < 16; ++kk) {
            const short8 af = hAp[kk * 64];   // ds_read_b128, conflict-free
            acc[0] = __builtin_amdgcn_mfma_f32_16x16x32_bf16(af, bfrag[0][kk], acc[0], 0, 0, 0);
            acc[1] = __builtin_amdgcn_mfma_f32_16x16x32_bf16(af, bfrag[1][kk], acc[1], 0, 0, 0);
            acc[2] = __builtin_amdgcn_mfma_f32_16x16x32_bf16(af, bfrag[2][kk], acc[2], 0, 0, 0);
            const short8 b3 = btp[kk * 64];   // LDS tile, conflict-free
            acc[3] = __builtin_amdgcn_mfma_f32_16x16x32_bf16(af, b3, acc[3], 0, 0, 0);
        }
        __syncthreads();   // all hB reads done
        #pragma unroll
        for (int tile = 0; tile < 4; ++tile) {
            #pragma unroll
            for (int r = 0; r < 4; ++r) {
                const float v = tanh_fast(acc[tile][r] + ep[r][tile]);
                *reinterpret_cast<unsigned short*>(hc + Bb[tile] + r * 16) = f2bf(v);
            }
        }
        __syncthreads();   // h_new visible
    }

    // FC epilogue: out[b0+rb][c] = sum_j h[rb][j]*W_fc[c][j] + b_fc[c]
    if (tid < 256) {
        const int rb = tid >> 4, c = tid & 15;
        float s = b_fc[c];
        #pragma unroll 4
        for (int j8 = 0; j8 < HIDD / 8; ++j8) {
            const int base = (j8 >> 2) * 1024 + (j8 & 3) * 256 + rb * 16;
            const short8 hv = *reinterpret_cast<const short8*>(hc + base);
            const float* wf = W_fc + c * HIDD + j8 * 8;
            #pragma unroll
            for (int i = 0; i < 8; ++i)
                s += bfu((unsigned short)hv[i]) * wf[i];
        }
        out[(b0 + rb) * NCLS + c] = s;
    }
}

// ---------------------------------------------------------------------------
// Round-1 fallback (used only if ws_size is too small for the EP table).
__global__ void cvt_kernel(const float* __restrict__ W_ih,
                           const float* __restrict__ W_hh,
                           const float* __restrict__ b_ih,
                           const float* __restrict__ b_hh,
                           unsigned short* __restrict__ Wpk,
                           unsigned short* __restrict__ Wipk,
                           float* __restrict__ bias) {
    const int NW = HIDD * HIDD;
    const int NI = HIDD * EMBD;
    int gid = blockIdx.x * blockDim.x + threadIdx.x;
    if (gid < NW) {
        int j = gid >> 9;
        int k = gid & (HIDD - 1);
        Wpk[((k >> 2) * HIDD + j) * 4 + (k & 3)] = f2bf(W_hh[gid]);
    } else if (gid < NW + NI) {
        int g = gid - NW;
        int j = g >> 8;
        int e = g & (EMBD - 1);
        Wipk[((e >> 2) * HIDD + j) * 4 + (e & 3)] = f2bf(W_ih[g]);
    } else if (gid < NW + NI + HIDD) {
        int j = gid - NW - NI;
        bias[j] = b_ih[j] + b_hh[j];
    }
}

__global__ __launch_bounds__(512) void rnn_kernel(
    const int*            __restrict__ x,
    const float*          __restrict__ emb,
    const unsigned short* __restrict__ Wpk,
    const unsigned short* __restrict__ Wipk,
    const float*          __restrict__ bias,
    const float*          __restrict__ W_fc,
    const float*          __restrict__ b_fc,
    float*                __restrict__ out) {

    __shared__ __align__(16) float hL[HIDD];
    __shared__ __align__(16) float xe[EMBD];
    __shared__ float red[512];

    const int tid = threadIdx.x;
    const int b   = blockIdx.x;
    const int j   = tid;

    hL[j] = 0.0f;
    const float bj = bias[j];

    const ushort4* Wp4 = reinterpret_cast<const ushort4*>(Wpk);
    const ushort4* Wi4 = reinterpret_cast<const ushort4*>(Wipk);

    for (int t = 0; t < SEQ; ++t) {
        const int tok = x[t * BATCH + b];
        if (tid < EMBD) xe[tid] = emb[tok * EMBD + tid];
        __syncthreads();

        float a0 = bj, a1 = 0.0f;
        #pragma unroll 8
        for (int e4 = 0; e4 < EMBD / 4; ++e4) {
            const float4 xv = *reinterpret_cast<const float4*>(&xe[e4 * 4]);
            const ushort4 w = Wi4[e4 * HIDD + j];
            a0 += xv.x * bfu(w.x) + xv.y * bfu(w.y);
            a1 += xv.z * bfu(w.z) + xv.w * bfu(w.w);
        }
        #pragma unroll 8
        for (int k4 = 0; k4 < HIDD / 4; ++k4) {
            const float4 hv = *reinterpret_cast<const float4*>(&hL[k4 * 4]);
            const ushort4 w = Wp4[k4 * HIDD + j];
            a0 += hv.x * bfu(w.x) + hv.y * bfu(w.y);
            a1 += hv.z * bfu(w.z) + hv.w * bfu(w.w);
        }
        __syncthreads();
        hL[j] = tanhf(a0 + a1);
    }
    __syncthreads();

    {
        const int c  = tid >> 5;
        const int ks = tid & 31;
        float p = 0.0f;
        #pragma unroll
        for (int jj = 0; jj < HIDD / 32; ++jj) {
            const int jd = ks * (HIDD / 32) + jj;
            p += hL[jd] * W_fc[c * HIDD + jd];
        }
        red[tid] = p;
        __syncthreads();
        if (tid < NCLS) {
            float s = b_fc[tid];
            #pragma unroll
            for (int i = 0; i < 32; ++i) s += red[tid * 32 + i];
            out[b * NCLS + tid] = s;
        }
    }
}

// ---------------------------------------------------------------------------
extern "C" void kernel_launch(void* const* d_in, const int* in_sizes, int n_in,
                              void* d_out, int out_size, void* d_ws, size_t ws_size,
                              hipStream_t stream) {
    const int*   x    = (const int*)  d_in[0];
    const float* emb  = (const float*)d_in[1];
    const float* W_ih = (const float*)d_in[2];
    const float* W_hh = (const float*)d_in[3];
    const float* b_ih = (const float*)d_in[4];
    const float* b_hh = (const float*)d_in[5];
    const float* W_fc = (const float*)d_in[6];
    const float* b_fc = (const float*)d_in[7];
    float* out = (float*)d_out;

    const size_t WHH_B = (size_t)HIDD * HIDD * 2;          // 512 KB bf16 W_hh
    const size_t EPN   = (size_t)VOCAB * HIDD;             // 16.384M entries

    if (ws_size >= WHH_B + EPN * 4) {
        unsigned short* Whh_b = (unsigned short*)d_ws;
        float* EP = (float*)((char*)d_ws + WHH_B);
        cvt_whh<<<(HIDD * HIDD) / 256, 256, 0, stream>>>(W_hh, Whh_b);
        ep_gemm<float><<<dim3(VOCAB / 64, HIDD / 16), 256, 0, stream>>>(
            emb, W_ih, b_ih, b_hh, EP);
        rnn_mfma<float><<<BATCH / 16, 512, 0, stream>>>(
            x, Whh_b, EP, W_fc, b_fc, out);
    } else if (ws_size >= WHH_B + EPN * 2) {
        unsigned short* Whh_b = (unsigned short*)d_ws;
        unsigned short* EP = (unsigned short*)((char*)d_ws + WHH_B);
        cvt_whh<<<(HIDD * HIDD) / 256, 256, 0, stream>>>(W_hh, Whh_b);
        ep_gemm<unsigned short><<<dim3(VOCAB / 64, HIDD / 16), 256, 0, stream>>>(
            emb, W_ih, b_ih, b_hh, EP);
        rnn_mfma<unsigned short><<<BATCH / 16, 512, 0, stream>>>(
            x, Whh_b, EP, W_fc, b_fc, out);
    } else {
        unsigned short* Wpk  = (unsigned short*)d_ws;
        unsigned short* Wipk = Wpk + HIDD * HIDD;
        float*          bias = (float*)(Wipk + HIDD * EMBD);
        const int total = HIDD * HIDD + HIDD * EMBD + HIDD;
        cvt_kernel<<<(total + 255) / 256, 256, 0, stream>>>(
            W_ih, W_hh, b_ih, b_hh, Wpk, Wipk, bias);
        rnn_kernel<<<BATCH, 512, 0, stream>>>(
            x, emb, Wpk, Wipk, bias, W_fc, b_fc, out);
    }
}

// Round 3
// 1519.540 us; speedup vs baseline: 3.7832x; 1.1079x over previous
//
#include <hip/hip_runtime.h>
#include <hip/hip_bf16.h>

#define SEQ   512
#define BATCH 128
#define EMBD  256
#define HIDD  512
#define NCLS  16
#define VOCAB 32000

typedef unsigned long long u64;
typedef __attribute__((ext_vector_type(8))) short  short8;
typedef __attribute__((ext_vector_type(4))) float  f32x4;

__device__ __forceinline__ float bfu(unsigned short u) {
    return __uint_as_float(((unsigned int)u) << 16);
}
__device__ __forceinline__ unsigned short f2bf(float f) {
    __hip_bfloat16 h = __float2bfloat16(f);
    return *reinterpret_cast<unsigned short*>(&h);
}
__device__ __forceinline__ float tanh_fast(float x) {
    float xc = fminf(fmaxf(x, -12.f), 12.f);
    float e  = __expf(2.f * xc);
    return 1.f - 2.f / (e + 1.f);
}
__device__ __forceinline__ void ep_store(float* p, float v)          { *p = v; }
__device__ __forceinline__ void ep_store(unsigned short* p, float v) { *p = f2bf(v); }
__device__ __forceinline__ void ld_ep4(const float* p, float* o) {
    float4 v = *reinterpret_cast<const float4*>(p);
    o[0] = v.x; o[1] = v.y; o[2] = v.z; o[3] = v.w;
}
__device__ __forceinline__ void ld_ep4(const unsigned short* p, float* o) {
    ushort4 v = *reinterpret_cast<const ushort4*>(p);
    o[0] = bfu(v.x); o[1] = bfu(v.y); o[2] = bfu(v.z); o[3] = bfu(v.w);
}

// ---------------------------------------------------------------------------
__global__ void zero_hex(u64* __restrict__ hex) {
    hex[blockIdx.x * 256 + threadIdx.x] = 0ull;   // grid 256 -> 65536 u64 = 512 KB
}

__global__ void cvt_whh(const float* __restrict__ W, unsigned short* __restrict__ Wb) {
    int i = blockIdx.x * 256 + threadIdx.x;
    if (i < HIDD * HIDD) Wb[i] = f2bf(W[i]);
}

// ---------------------------------------------------------------------------
// EP[v][j] = emb[v]·W_ih[j] + b_ih[j] + b_hh[j].  grid 500 x 256 thr.
// Wave w: vocab mtile = bx*4+w (16 rows), loops all 32 ntiles; emb read ONCE.
template <typename EPT>
__global__ __launch_bounds__(256) void ep_gemm2(
    const float* __restrict__ emb, const float* __restrict__ W_ih,
    const float* __restrict__ b_ih, const float* __restrict__ b_hh,
    EPT* __restrict__ EP) {
    const int w = threadIdx.x >> 6, l = threadIdx.x & 63;
    const int n = l & 15, lk = l >> 4;
    const int mtile = blockIdx.x * 4 + w;
    const int arow  = mtile * 16 + n;

    short8 areg[8];
    #pragma unroll
    for (int kk = 0; kk < 8; ++kk) {
        const int k0 = kk * 32 + lk * 8;
        const float4 a0 = *reinterpret_cast<const float4*>(emb + arow * EMBD + k0);
        const float4 a1 = *reinterpret_cast<const float4*>(emb + arow * EMBD + k0 + 4);
        short8 t;
        t[0]=(short)f2bf(a0.x); t[1]=(short)f2bf(a0.y); t[2]=(short)f2bf(a0.z); t[3]=(short)f2bf(a0.w);
        t[4]=(short)f2bf(a1.x); t[5]=(short)f2bf(a1.y); t[6]=(short)f2bf(a1.z); t[7]=(short)f2bf(a1.w);
        areg[kk] = t;
    }

    for (int nt = 0; nt < 32; ++nt) {
        const int col  = nt * 16 + n;
        const float bias = b_ih[col] + b_hh[col];
        f32x4 accA = {0.f,0.f,0.f,0.f}, accB = {0.f,0.f,0.f,0.f};
        #pragma unroll
        for (int kk = 0; kk < 8; ++kk) {
            const int k0 = kk * 32 + lk * 8;
            const float4 c0 = *reinterpret_cast<const float4*>(W_ih + col * EMBD + k0);
            const float4 c1 = *reinterpret_cast<const float4*>(W_ih + col * EMBD + k0 + 4);
            short8 bb;
            bb[0]=(short)f2bf(c0.x); bb[1]=(short)f2bf(c0.y); bb[2]=(short)f2bf(c0.z); bb[3]=(short)f2bf(c0.w);
            bb[4]=(short)f2bf(c1.x); bb[5]=(short)f2bf(c1.y); bb[6]=(short)f2bf(c1.z); bb[7]=(short)f2bf(c1.w);
            if (kk & 1) accB = __builtin_amdgcn_mfma_f32_16x16x32_bf16(areg[kk], bb, accB, 0, 0, 0);
            else        accA = __builtin_amdgcn_mfma_f32_16x16x32_bf16(areg[kk], bb, accA, 0, 0, 0);
        }
        const f32x4 ac = accA + accB;
        #pragma unroll
        for (int r = 0; r < 4; ++r)
            ep_store(EP + (size_t)(mtile * 16 + lk * 4 + r) * HIDD + col, ac[r] + bias);
    }
}

// ---------------------------------------------------------------------------
// Multi-CU RNN. 32 WGs = 8 groups x 4 col-splits. 256 thr (4 waves).
// A = W_hh rows (in 128 VGPRs/lane), B = h (staged to LDS in B-frag order).
// h exchange: Hex[g][parity][4096] u64 quanta {tag:u32 | bf16 hi | bf16 lo}.
__device__ __forceinline__ void publish(u64* nxt, unsigned tag, float hv[2][4],
                                        const int* qoff) {
    #pragma unroll
    for (int tile = 0; tile < 2; ++tile) {
        u64 q0 = ((u64)tag << 32) | ((u64)f2bf(hv[tile][1]) << 16) | f2bf(hv[tile][0]);
        u64 q1 = ((u64)tag << 32) | ((u64)f2bf(hv[tile][3]) << 16) | f2bf(hv[tile][2]);
        __hip_atomic_store(nxt + qoff[tile],     q0, __ATOMIC_RELAXED, __HIP_MEMORY_SCOPE_AGENT);
        __hip_atomic_store(nxt + qoff[tile] + 1, q1, __ATOMIC_RELAXED, __HIP_MEMORY_SCOPE_AGENT);
    }
}

template <typename EPT>
__global__ __launch_bounds__(256, 1) void rnn3(
    const int*            __restrict__ x,
    const unsigned short* __restrict__ Whh,
    const EPT*            __restrict__ EP,
    const float*          __restrict__ W_fc,
    const float*          __restrict__ b_fc,
    float*                __restrict__ out,
    u64*                  __restrict__ Hex) {

    const int g = blockIdx.x >> 2, s = blockIdx.x & 3;
    const int tid = threadIdx.x, l = tid & 63;
    const int w = tid >> 6, n = l & 15, lk = l >> 4;
    const int b0 = g * 16;

    __shared__ short8 hfrag[1024];   // 16 KB, B-frag order: block = kk*64 + lane

    const int jb[2] = { s * 128 + w * 32, s * 128 + w * 32 + 16 };

    int qoff[2], blkT[2], offT[2];
    #pragma unroll
    for (int tile = 0; tile < 2; ++tile) {
        const int j0  = jb[tile] + lk * 4;
        const int blk = ((j0 >> 5) << 6) | n | (((j0 >> 3) & 3) << 4);
        qoff[tile] = blk * 4 + ((j0 >> 1) & 3);
        blkT[tile] = blk;
        offT[tile] = (j0 & 4) ? 8 : 0;
    }

    u64* const hex_g = Hex + (size_t)g * 2 * 4096;

    // ---- t = 0: h1 = tanh(EP[tok0]) (h0 = 0, no matvec) ----
    float hv[2][4];
    {
        const int tok = x[b0 + n];
        float e0[4], e1[4];
        ld_ep4(EP + (size_t)tok * HIDD + jb[0] + lk * 4, e0);
        ld_ep4(EP + (size_t)tok * HIDD + jb[1] + lk * 4, e1);
        #pragma unroll
        for (int r = 0; r < 4; ++r) { hv[0][r] = tanh_fast(e0[r]); hv[1][r] = tanh_fast(e1[r]); }
        publish(hex_g + 4096, 1u, hv, qoff);
    }

    // ---- register-resident A fragments (this wave's 32 weight rows) ----
    short8 af[2][16];
    #pragma unroll
    for (int tile = 0; tile < 2; ++tile)
        #pragma unroll
        for (int kk = 0; kk < 16; ++kk)
            af[tile][kk] = *reinterpret_cast<const short8*>(
                Whh + (size_t)(jb[tile] + n) * HIDD + kk * 32 + lk * 8);

    // prefetch ep for t=1
    float epc[2][4];
    {
        const int tok = x[BATCH + b0 + n];
        ld_ep4(EP + (size_t)tok * HIDD + jb[0] + lk * 4, epc[0]);
        ld_ep4(EP + (size_t)tok * HIDD + jb[1] + lk * 4, epc[1]);
    }

    for (int t = 1; t <= 511; ++t) {
        u64* const cur = hex_g + (size_t)(t & 1) * 4096;

        // stage own chunk from regs (LDS b64 writes, conflict-free)
        #pragma unroll
        for (int tile = 0; tile < 2; ++tile) {
            const u64 ownv = (u64)f2bf(hv[tile][0]) | ((u64)f2bf(hv[tile][1]) << 16)
                           | ((u64)f2bf(hv[tile][2]) << 32) | ((u64)f2bf(hv[tile][3]) << 48);
            *reinterpret_cast<u64*>(reinterpret_cast<char*>(hfrag) + blkT[tile] * 16 + offT[tile]) = ownv;
        }
        // stage remote chunks with tag-poll
        const unsigned tg = (unsigned)t;
        #pragma unroll
        for (int q = 0; q < 4; ++q) {
            if (q == s) continue;
            const int blk = q * 256 + tid;
            u64* p = cur + (size_t)blk * 4;
            u64 v0 = __hip_atomic_load(p + 0, __ATOMIC_RELAXED, __HIP_MEMORY_SCOPE_AGENT);
            u64 v1 = __hip_atomic_load(p + 1, __ATOMIC_RELAXED, __HIP_MEMORY_SCOPE_AGENT);
            u64 v2 = __hip_atomic_load(p + 2, __ATOMIC_RELAXED, __HIP_MEMORY_SCOPE_AGENT);
            u64 v3 = __hip_atomic_load(p + 3, __ATOMIC_RELAXED, __HIP_MEMORY_SCOPE_AGENT);
            int guard = 0;
            while ((unsigned)(v0 >> 32) != tg || (unsigned)(v1 >> 32) != tg ||
                   (unsigned)(v2 >> 32) != tg || (unsigned)(v3 >> 32) != tg) {
                __builtin_amdgcn_s_sleep(1);
                if ((unsigned)(v0 >> 32) != tg) v0 = __hip_atomic_load(p + 0, __ATOMIC_RELAXED, __HIP_MEMORY_SCOPE_AGENT);
                if ((unsigned)(v1 >> 32) != tg) v1 = __hip_atomic_load(p + 1, __ATOMIC_RELAXED, __HIP_MEMORY_SCOPE_AGENT);
                if ((unsigned)(v2 >> 32) != tg) v2 = __hip_atomic_load(p + 2, __ATOMIC_RELAXED, __HIP_MEMORY_SCOPE_AGENT);
                if ((unsigned)(v3 >> 32) != tg) v3 = __hip_atomic_load(p + 3, __ATOMIC_RELAXED, __HIP_MEMORY_SCOPE_AGENT);
                if (++guard > (1 << 24)) break;   // degrade to visible failure, never hang
            }
            short8 hb;
            hb[0] = (short)(unsigned short)v0; hb[1] = (short)(unsigned short)(v0 >> 16);
            hb[2] = (short)(unsigned short)v1; hb[3] = (short)(unsigned short)(v1 >> 16);
            hb[4] = (short)(unsigned short)v2; hb[5] = (short)(unsigned short)(v2 >> 16);
            hb[6] = (short)(unsigned short)v3; hb[7] = (short)(unsigned short)(v3 >> 16);
            hfrag[blk] = hb;
        }
        __syncthreads();

        // prefetch ep(t+1) — hidden under MFMA
        float epn[2][4];
        {
            const int tn = (t < 511) ? t + 1 : 511;
            const int tok = x[tn * BATCH + b0 + n];
            ld_ep4(EP + (size_t)tok * HIDD + jb[0] + lk * 4, epn[0]);
            ld_ep4(EP + (size_t)tok * HIDD + jb[1] + lk * 4, epn[1]);
        }

        // MFMA: D[j][n] = sum_k Whh[j][k] * h[n][k]  (4 chains)
        f32x4 a00 = {0.f,0.f,0.f,0.f}, a01 = {0.f,0.f,0.f,0.f};
        f32x4 a10 = {0.f,0.f,0.f,0.f}, a11 = {0.f,0.f,0.f,0.f};
        const short8* bp = hfrag + l;
        #pragma unroll
        for (int kk = 0; kk < 16; kk += 2) {
            const short8 bA = bp[kk * 64];
            const short8 bB = bp[(kk + 1) * 64];
            a00 = __builtin_amdgcn_mfma_f32_16x16x32_bf16(af[0][kk],     bA, a00, 0, 0, 0);
            a10 = __builtin_amdgcn_mfma_f32_16x16x32_bf16(af[1][kk],     bA, a10, 0, 0, 0);
            a01 = __builtin_amdgcn_mfma_f32_16x16x32_bf16(af[0][kk + 1], bB, a01, 0, 0, 0);
            a11 = __builtin_amdgcn_mfma_f32_16x16x32_bf16(af[1][kk + 1], bB, a11, 0, 0, 0);
        }
        const f32x4 A0 = a00 + a01, A1 = a10 + a11;

        #pragma unroll
        for (int r = 0; r < 4; ++r) {
            hv[0][r] = tanh_fast(A0[r] + epc[0][r]);
            hv[1][r] = tanh_fast(A1[r] + epc[1][r]);
        }
        publish(hex_g + (size_t)((t + 1) & 1) * 4096, (unsigned)(t + 1), hv, qoff);

        #pragma unroll
        for (int r = 0; r < 4; ++r) { epc[0][r] = epn[0][r]; epc[1][r] = epn[1][r]; }
        __syncthreads();   // all B-frag reads done before next stage overwrites
    }

    // ---- FC epilogue on split-0 WGs: out[b][c] = h512[b]·W_fc[c] + b_fc[c] ----
    if (s == 0) {
        #pragma unroll
        for (int tile = 0; tile < 2; ++tile) {
            const u64 ownv = (u64)f2bf(hv[tile][0]) | ((u64)f2bf(hv[tile][1]) << 16)
                           | ((u64)f2bf(hv[tile][2]) << 32) | ((u64)f2bf(hv[tile][3]) << 48);
            *reinterpret_cast<u64*>(reinterpret_cast<char*>(hfrag) + blkT[tile] * 16 + offT[tile]) = ownv;
        }
        u64* const cur = hex_g;   // parity (512)&1 = 0
        const unsigned tg = 512u;
        #pragma unroll
        for (int q = 1; q < 4; ++q) {
            const int blk = q * 256 + tid;
            u64* p = cur + (size_t)blk * 4;
            u64 v0 = __hip_atomic_load(p + 0, __ATOMIC_RELAXED, __HIP_MEMORY_SCOPE_AGENT);
            u64 v1 = __hip_atomic_load(p + 1, __ATOMIC_RELAXED, __HIP_MEMORY_SCOPE_AGENT);
            u64 v2 = __hip_atomic_load(p + 2, __ATOMIC_RELAXED, __HIP_MEMORY_SCOPE_AGENT);
            u64 v3 = __hip_atomic_load(p + 3, __ATOMIC_RELAXED, __HIP_MEMORY_SCOPE_AGENT);
            int guard = 0;
            while ((unsigned)(v0 >> 32) != tg || (unsigned)(v1 >> 32) != tg ||
                   (unsigned)(v2 >> 32) != tg || (unsigned)(v3 >> 32) != tg) {
                __builtin_amdgcn_s_sleep(1);
                if ((unsigned)(v0 >> 32) != tg) v0 = __hip_atomic_load(p + 0, __ATOMIC_RELAXED, __HIP_MEMORY_SCOPE_AGENT);
                if ((unsigned)(v1 >> 32) != tg) v1 = __hip_atomic_load(p + 1, __ATOMIC_RELAXED, __HIP_MEMORY_SCOPE_AGENT);
                if ((unsigned)(v2 >> 32) != tg) v2 = __hip_atomic_load(p + 2, __ATOMIC_RELAXED, __HIP_MEMORY_SCOPE_AGENT);
                if ((unsigned)(v3 >> 32) != tg) v3 = __hip_atomic_load(p + 3, __ATOMIC_RELAXED, __HIP_MEMORY_SCOPE_AGENT);
                if (++guard > (1 << 24)) break;
            }
            short8 hb;
            hb[0] = (short)(unsigned short)v0; hb[1] = (short)(unsigned short)(v0 >> 16);
            hb[2] = (short)(unsigned short)v1; hb[3] = (short)(unsigned short)(v1 >> 16);
            hb[4] = (short)(unsigned short)v2; hb[5] = (short)(unsigned short)(v2 >> 16);
            hb[6] = (short)(unsigned short)v3; hb[7] = (short)(unsigned short)(v3 >> 16);
            hfrag[blk] = hb;
        }
        __syncthreads();

        const int n2 = tid >> 4, c = tid & 15;
        float sum = b_fc[c];
        const unsigned short* hp = reinterpret_cast<const unsigned short*>(hfrag);
        for (int kk = 0; kk < 16; ++kk)
            #pragma unroll
            for (int lo = 0; lo < 4; ++lo) {
                const int bb = (kk << 6) | n2 | (lo << 4);
                #pragma unroll
                for (int i = 0; i < 8; ++i) {
                    const int j = kk * 32 + lo * 8 + i;
                    sum += bfu(hp[bb * 8 + i]) * W_fc[c * HIDD + j];
                }
            }
        out[(b0 + n2) * NCLS + c] = sum;
    }
}

// ---------------------------------------------------------------------------
// Tier-C fallback (round-1, known good) for small ws.
__global__ void cvt_kernel(const float* __restrict__ W_ih,
                           const float* __restrict__ W_hh,
                           const float* __restrict__ b_ih,
                           const float* __restrict__ b_hh,
                           unsigned short* __restrict__ Wpk,
                           unsigned short* __restrict__ Wipk,
                           float* __restrict__ bias) {
    const int NW = HIDD * HIDD;
    const int NI = HIDD * EMBD;
    int gid = blockIdx.x * blockDim.x + threadIdx.x;
    if (gid < NW) {
        int j = gid >> 9, k = gid & (HIDD - 1);
        Wpk[((k >> 2) * HIDD + j) * 4 + (k & 3)] = f2bf(W_hh[gid]);
    } else if (gid < NW + NI) {
        int g2 = gid - NW, j = g2 >> 8, e = g2 & (EMBD - 1);
        Wipk[((e >> 2) * HIDD + j) * 4 + (e & 3)] = f2bf(W_ih[g2]);
    } else if (gid < NW + NI + HIDD) {
        int j = gid - NW - NI;
        bias[j] = b_ih[j] + b_hh[j];
    }
}

__global__ __launch_bounds__(512) void rnn_kernel(
    const int* __restrict__ x, const float* __restrict__ emb,
    const unsigned short* __restrict__ Wpk, const unsigned short* __restrict__ Wipk,
    const float* __restrict__ bias, const float* __restrict__ W_fc,
    const float* __restrict__ b_fc, float* __restrict__ out) {
    __shared__ __align__(16) float hL[HIDD];
    __shared__ __align__(16) float xe[EMBD];
    __shared__ float red[512];
    const int tid = threadIdx.x, b = blockIdx.x, j = tid;
    hL[j] = 0.0f;
    const float bj = bias[j];
    const ushort4* Wp4 = reinterpret_cast<const ushort4*>(Wpk);
    const ushort4* Wi4 = reinterpret_cast<const ushort4*>(Wipk);
    for (int t = 0; t < SEQ; ++t) {
        const int tok = x[t * BATCH + b];
        if (tid < EMBD) xe[tid] = emb[tok * EMBD + tid];
        __syncthreads();
        float a0 = bj, a1 = 0.0f;
        #pragma unroll 8
        for (int e4 = 0; e4 < EMBD / 4; ++e4) {
            const float4 xv = *reinterpret_cast<const float4*>(&xe[e4 * 4]);
            const ushort4 w = Wi4[e4 * HIDD + j];
            a0 += xv.x * bfu(w.x) + xv.y * bfu(w.y);
            a1 += xv.z * bfu(w.z) + xv.w * bfu(w.w);
        }
        #pragma unroll 8
        for (int k4 = 0; k4 < HIDD / 4; ++k4) {
            const float4 hvv = *reinterpret_cast<const float4*>(&hL[k4 * 4]);
            const ushort4 w = Wp4[k4 * HIDD + j];
            a0 += hvv.x * bfu(w.x) + hvv.y * bfu(w.y);
            a1 += hvv.z * bfu(w.z) + hvv.w * bfu(w.w);
        }
        __syncthreads();
        hL[j] = tanhf(a0 + a1);
    }
    __syncthreads();
    {
        const int c = tid >> 5, ks = tid & 31;
        float p = 0.0f;
        #pragma unroll
        for (int jj = 0; jj < HIDD / 32; ++jj) {
            const int jd = ks * (HIDD / 32) + jj;
            p += hL[jd] * W_fc[c * HIDD + jd];
        }
        red[tid] = p;
        __syncthreads();
        if (tid < NCLS) {
            float ss = b_fc[tid];
            #pragma unroll
            for (int i = 0; i < 32; ++i) ss += red[tid * 32 + i];
            out[b * NCLS + tid] = ss;
        }
    }
}

// ---------------------------------------------------------------------------
extern "C" void kernel_launch(void* const* d_in, const int* in_sizes, int n_in,
                              void* d_out, int out_size, void* d_ws, size_t ws_size,
                              hipStream_t stream) {
    const int*   x    = (const int*)  d_in[0];
    const float* emb  = (const float*)d_in[1];
    const float* W_ih = (const float*)d_in[2];
    const float* W_hh = (const float*)d_in[3];
    const float* b_ih = (const float*)d_in[4];
    const float* b_hh = (const float*)d_in[5];
    const float* W_fc = (const float*)d_in[6];
    const float* b_fc = (const float*)d_in[7];
    float* out = (float*)d_out;

    const size_t HEX_B = 8ull * 2 * 4096 * 8;           // 512 KB
    const size_t WHH_B = (size_t)HIDD * HIDD * 2;       // 512 KB
    const size_t EPN   = (size_t)VOCAB * HIDD;

    if (ws_size >= HEX_B + WHH_B + EPN * 4) {
        u64*            Hex   = (u64*)d_ws;
        unsigned short* Whh_b = (unsigned short*)((char*)d_ws + HEX_B);
        float*          EP    = (float*)((char*)d_ws + HEX_B + WHH_B);
        zero_hex<<<256, 256, 0, stream>>>(Hex);
        cvt_whh<<<(HIDD * HIDD) / 256, 256, 0, stream>>>(W_hh, Whh_b);
        ep_gemm2<float><<<VOCAB / 64, 256, 0, stream>>>(emb, W_ih, b_ih, b_hh, EP);
        rnn3<float><<<32, 256, 0, stream>>>(x, Whh_b, EP, W_fc, b_fc, out, Hex);
    } else if (ws_size >= HEX_B + WHH_B + EPN * 2) {
        u64*            Hex   = (u64*)d_ws;
        unsigned short* Whh_b = (unsigned short*)((char*)d_ws + HEX_B);
        unsigned short* EP    = (unsigned short*)((char*)d_ws + HEX_B + WHH_B);
        zero_hex<<<256, 256, 0, stream>>>(Hex);
        cvt_whh<<<(HIDD * HIDD) / 256, 256, 0, stream>>>(W_hh, Whh_b);
        ep_gemm2<unsigned short><<<VOCAB / 64, 256, 0, stream>>>(emb, W_ih, b_ih, b_hh, EP);
        rnn3<unsigned short><<<32, 256, 0, stream>>>(x, Whh_b, EP, W_fc, b_fc, out, Hex);
    } else {
        unsigned short* Wpk  = (unsigned short*)d_ws;
        unsigned short* Wipk = Wpk + HIDD * HIDD;
        float*          bias = (float*)(Wipk + HIDD * EMBD);
        const int total = HIDD * HIDD + HIDD * EMBD + HIDD;
        cvt_kernel<<<(total + 255) / 256, 256, 0, stream>>>(W_ih, W_hh, b_ih, b_hh, Wpk, Wipk, bias);
        rnn_kernel<<<BATCH, 512, 0, stream>>>(x, emb, Wpk, Wipk, bias, W_fc, b_fc, out);
    }
}